// Round 3
// baseline (263.017 us; speedup 1.0000x reference)
//
#include <hip/hip_runtime.h>

#define NV  16
#define NB  64
#define NT  256
#define NH  128
#define NFC 256
#define NC  10

typedef _Float16 half8  __attribute__((ext_vector_type(8)));
typedef float    f32x4  __attribute__((ext_vector_type(4)));

// One workgroup = one variable v, FOUR batch rows. 8 waves, 256 WGs -> all CUs.
// Per step: gh^T = Whh(384n x 128k) * h^T(128k x 16b) via mfma 16x16x32 f16,
// N=16 slots with only rows 0..3 valid (rows 4..15 of the B-frag stay zero).
// Wave w owns h-columns [w*16, w*16+16) of all 3 gates: 12 MFMAs/step.
// C layout: col(batch row) = lane&15, row(h-col) = (lane>>4)*4 + reg.
// Lane work-sharing: lane (rb + 4s, m4) [rb=r&3, s=r>>2] processes the single
// update (row rb, h-col j = j0+s) after redistributing acc via shfl_xor
// masks 4/8/12 (within the 16-lane r-group).
// Activation algebra (prescaled weights, division-minimized) as round 2:
//   srs -> r = rcp(1+exp2(srs)); a = exp2(szs); b = exp2(-ccs)
//   h' = [a(1-b) + h(1+b)] / [(1+a)(1+b)]
__global__ __launch_bounds__(512, 2) void gru_scan_kernel(
    const float* __restrict__ x,   const float* __restrict__ Wih,
    const float* __restrict__ Whh, const float* __restrict__ bih,
    const float* __restrict__ bhh, const float* __restrict__ Wp,
    const float* __restrict__ bp,  float* __restrict__ concat_ws)
{
    __shared__ __align__(16) _Float16 frag[2][2048];  // 2 x 4KB: [kb*512 + lane*8]
    __shared__ float xT[NT][5];                       // x transposed, 4 rows padded
    __shared__ float pc[8][4];

    const int tid = threadIdx.x;
    const int w   = tid >> 6;        // wave 0..7
    const int l   = tid & 63;
    const int r   = l & 15;
    const int m4  = l >> 4;          // 0..3
    const int rb  = r & 3;           // batch row 0..3
    const int s   = r >> 2;          // q-slot this lane processes
    const int bid = blockIdx.x;
    const int v   = bid >> 4;        // variable
    const int b0  = (bid & 15) << 2; // batch chunk base (4 rows)
    const int j0  = (w << 4) + (m4 << 2);
    const int j   = j0 + s;          // this lane's single h-column

    constexpr float L2E = 1.44269504088896340736f;
    const float SCL0 = -L2E, SCL2 = 2.0f * L2E;

    // ---- stage x[v, b0+rr, :] into xT[t][rr] ----
    {
        const int rr = tid >> 7;          // 0..3
        const int t0 = (tid & 127) << 1;  // 0..254
        const float2 xv = *(const float2*)(x + (size_t)(v * NB + b0 + rr) * NT + t0);
        xT[t0][rr] = xv.x; xT[t0 + 1][rr] = xv.y;
    }
    // zero BOTH frag buffers (rows 4..15 stay zero forever; h0 = 0)
    {
        unsigned* fz = (unsigned*)frag;
        #pragma unroll
        for (int i = 0; i < 4; ++i) fz[tid + i * 512] = 0u;
    }

    // ---- preload PRESCALED Whh A-fragments: A[n=l&15][k=kb*32+(l>>4)*8+e] ----
    half8 afr[3][4];
    #pragma unroll
    for (int g = 0; g < 3; ++g) {
        const float sc = (g == 2) ? SCL2 : SCL0;
        #pragma unroll
        for (int kb = 0; kb < 4; ++kb) {
            const float* wpp = Whh + (size_t)(v * 384 + g * 128 + (w << 4) + r) * 128
                             + kb * 32 + m4 * 8;
            float4 lo = *(const float4*)wpp;
            float4 hi = *(const float4*)(wpp + 4);
            half8 hf;
            hf[0]=(_Float16)(sc*lo.x); hf[1]=(_Float16)(sc*lo.y);
            hf[2]=(_Float16)(sc*lo.z); hf[3]=(_Float16)(sc*lo.w);
            hf[4]=(_Float16)(sc*hi.x); hf[5]=(_Float16)(sc*hi.y);
            hf[6]=(_Float16)(sc*hi.z); hf[7]=(_Float16)(sc*hi.w);
            afr[g][kb] = hf;
        }
    }

    // MFMA C-init = prescaled bhh for columns j0..j0+3 (full 4q per lane)
    f32x4 c0i, c1i, c2i;
    #pragma unroll
    for (int q = 0; q < 4; ++q) {
        c0i[q] = SCL0 * bhh[v * 384 +   0 + j0 + q];
        c1i[q] = SCL0 * bhh[v * 384 + 128 + j0 + q];
        c2i[q] = SCL2 * bhh[v * 384 + 256 + j0 + q];
    }
    // per-lane single-column prescaled input-side params
    float wihs_[3], bihs_[3];
    #pragma unroll
    for (int g = 0; g < 3; ++g) {
        const float sc = (g == 2) ? SCL2 : SCL0;
        wihs_[g] = sc * Wih[v * 384 + g * 128 + j];
        bihs_[g] = sc * bih[v * 384 + g * 128 + j];
    }
    const float wpj = Wp[v * NH + j];

    float h_old = 0.f;

    // frag b16-write offset for element (row rb, col j)
    const int fwoff = (j >> 5) * 512 + (rb + 16 * ((j & 31) >> 3)) * 8 + (j & 7);
    const int rdoff = l * 8;

    __syncthreads();

    auto step = [&](const _Float16* __restrict__ fb, _Float16* __restrict__ fwb,
                    const float xr) {
        half8 bfr[4];
        #pragma unroll
        for (int kb = 0; kb < 4; ++kb)
            bfr[kb] = *(const half8*)(fb + kb * 512 + rdoff);

        f32x4 acc0 = __builtin_amdgcn_mfma_f32_16x16x32_f16(afr[0][0], bfr[0], c0i, 0, 0, 0);
        f32x4 acc1 = __builtin_amdgcn_mfma_f32_16x16x32_f16(afr[1][0], bfr[0], c1i, 0, 0, 0);
        f32x4 acc2 = __builtin_amdgcn_mfma_f32_16x16x32_f16(afr[2][0], bfr[0], c2i, 0, 0, 0);
        #pragma unroll
        for (int kb = 1; kb < 4; ++kb) {
            acc0 = __builtin_amdgcn_mfma_f32_16x16x32_f16(afr[0][kb], bfr[kb], acc0, 0, 0, 0);
            acc1 = __builtin_amdgcn_mfma_f32_16x16x32_f16(afr[1][kb], bfr[kb], acc1, 0, 0, 0);
            acc2 = __builtin_amdgcn_mfma_f32_16x16x32_f16(afr[2][kb], bfr[kb], acc2, 0, 0, 0);
        }

        // redistribute: lane (rb+4s) takes q-slot s of producer lane rb
        const bool sel1 = (s & 1) != 0, sel2 = (s & 2) != 0;
        float gv[3];
        #pragma unroll
        for (int g = 0; g < 3; ++g) {
            const f32x4& a4 = (g == 0) ? acc0 : (g == 1) ? acc1 : acc2;
            const float t4  = __shfl_xor(a4[1], 4, 64);
            const float t8  = __shfl_xor(a4[2], 8, 64);
            const float t12 = __shfl_xor(a4[3], 12, 64);
            const float lo  = sel1 ? t4  : a4[0];
            const float hi  = sel1 ? t12 : t8;
            gv[g] = sel2 ? hi : lo;
        }

        const float srs = fmaf(xr, wihs_[0], bihs_[0]) + gv[0];
        const float szs = fmaf(xr, wihs_[1], bihs_[1]) + gv[1];
        const float gns = fmaf(xr, wihs_[2], bihs_[2]);
        const float rg  = __builtin_amdgcn_rcpf(1.f + __builtin_amdgcn_exp2f(srs));
        const float a   = __builtin_amdgcn_exp2f(szs);
        const float ccs = fmaf(rg, gv[2], gns);
        const float b   = __builtin_amdgcn_exp2f(-ccs);
        const float h   = h_old;
        const float num = fmaf(-a, b, a) + fmaf(h, b, h);   // a(1-b) + h(1+b)
        const float den = (1.f + a) * (1.f + b);
        const float hn  = num * __builtin_amdgcn_rcpf(den);
        h_old = hn;
        fwb[fwoff] = (_Float16)hn;   // single b16 write
        __syncthreads();
    };

    for (int t = 0; t < NT; t += 2) {
        const float xa = xT[t][rb];
        const float xb = xT[t + 1][rb];
        step(&frag[0][0], &frag[1][0], xa);
        step(&frag[1][0], &frag[0][0], xb);
    }

    // ---- epilogue: concat[b0+rb][v] = sum_j h[rb][j]*Wp[v][j] + bp[v] ----
    float partial = h_old * wpj;
    partial += __shfl_xor(partial, 4, 64);
    partial += __shfl_xor(partial, 8, 64);
    partial += __shfl_xor(partial, 16, 64);
    partial += __shfl_xor(partial, 32, 64);
    if (l < 4) pc[w][l] = partial;
    __syncthreads();
    if (tid < 4) {
        float acc = bp[v];
        #pragma unroll
        for (int ww = 0; ww < 8; ++ww) acc += pc[ww][tid];
        concat_ws[(b0 + tid) * NV + v] = acc;
    }
}

// FC head: concat[64][16] -> relu(W1) -> W2 -> out[64][10]. One small block.
__global__ __launch_bounds__(256, 1) void fc_kernel(
    const float* __restrict__ cws, const float* __restrict__ W1,
    const float* __restrict__ b1,  const float* __restrict__ W2,
    const float* __restrict__ b2,  float* __restrict__ out)
{
    __shared__ float cc[NB][NV + 1];
    __shared__ float hfc[NB][NFC + 1];
    const int tid = threadIdx.x;
    for (int i = tid; i < NB * NV; i += 256) cc[i >> 4][i & 15] = cws[i];
    __syncthreads();

    float w1r[NV];
    #pragma unroll
    for (int q = 0; q < NV; q += 4) {
        float4 t4 = *(const float4*)(W1 + tid * NV + q);
        w1r[q] = t4.x; w1r[q+1] = t4.y; w1r[q+2] = t4.z; w1r[q+3] = t4.w;
    }
    const float bb = b1[tid];
    for (int b = 0; b < NB; ++b) {
        float sacc = bb;
        #pragma unroll
        for (int q = 0; q < NV; ++q) sacc = fmaf(cc[b][q], w1r[q], sacc);
        hfc[b][tid] = fmaxf(sacc, 0.f);
    }
    __syncthreads();

    for (int idx = tid; idx < NB * NC; idx += 256) {
        const int b = idx / NC, c = idx % NC;
        const float* w2r = W2 + c * NFC;
        float sacc = b2[c];
        #pragma unroll 4
        for (int f = 0; f < NFC; f += 4) {
            float4 wv = *(const float4*)(w2r + f);
            sacc = fmaf(hfc[b][f+0], wv.x, sacc);
            sacc = fmaf(hfc[b][f+1], wv.y, sacc);
            sacc = fmaf(hfc[b][f+2], wv.z, sacc);
            sacc = fmaf(hfc[b][f+3], wv.w, sacc);
        }
        out[idx] = sacc;
    }
}

extern "C" void kernel_launch(void* const* d_in, const int* in_sizes, int n_in,
                              void* d_out, int out_size, void* d_ws, size_t ws_size,
                              hipStream_t stream) {
    const float* x   = (const float*)d_in[0];
    const float* Wih = (const float*)d_in[1];
    const float* Whh = (const float*)d_in[2];
    const float* bih = (const float*)d_in[3];
    const float* bhh = (const float*)d_in[4];
    const float* Wp  = (const float*)d_in[5];
    const float* bp  = (const float*)d_in[6];
    const float* W1  = (const float*)d_in[7];
    const float* b1  = (const float*)d_in[8];
    const float* W2  = (const float*)d_in[9];
    const float* b2  = (const float*)d_in[10];
    float* out = (float*)d_out;
    float* cws = (float*)d_ws;  // concat scratch: 64*16 f32 = 4 KB

    gru_scan_kernel<<<dim3(256), dim3(512), 0, stream>>>(x, Wih, Whh, bih, bhh, Wp, bp, cws);
    fc_kernel<<<dim3(1), dim3(256), 0, stream>>>(cws, W1, b1, W2, b2, out);
}

// Round 5
// 202.920 us; speedup vs baseline: 1.2962x; 1.2962x over previous
//
#include <hip/hip_runtime.h>

#define NV  16
#define NB  64
#define NT  256
#define NH  128
#define NFC 256
#define NC  10

typedef _Float16 half8  __attribute__((ext_vector_type(8)));
typedef _Float16 half2v __attribute__((ext_vector_type(2)));
typedef float    f32x4  __attribute__((ext_vector_type(4)));

// One workgroup = one variable v, EIGHT batch rows. 8 waves, 128 WGs (128 CUs).
// Per step: gh^T = Whh(384n x 128k) * h^T(128k x 16b) via mfma 16x16x32 f16.
// B rows n and n+8 both hold h[row n] (handlers double-write h), so D column
// n duplicates n&7: EVERY lane (l&15 = rbh or rbh+8) holds the full gh for
// batch row rbh = l&7, cols j0..j0+3, in its OWN accumulator. NO shuffles:
// handler s = (l>>3)&1 picks acc regs {2s, 2s+1} (cols jh = j0+2s, jh+1)
// with two v_cndmask per gate. Expansion 2, ILP 2.
// C layout (verified r2): col(B row) = lane&15, row(h-col) = (lane>>4)*4+reg.
// Activation algebra (prescaled weights, division-minimized, verified r2/r3):
//   r = rcp(1+exp2(srs)); a = exp2(szs); b = exp2(-ccs)
//   h' = [a(1-b) + h(1+b)] / [(1+a)(1+b)] ; num = fma(b, h-a, a+h)
// bih of r/z gates folded into MFMA C-init; n-gate bih stays outside the
// r-multiply.
__global__ __launch_bounds__(512, 2) void gru_scan_kernel(
    const float* __restrict__ x,   const float* __restrict__ Wih,
    const float* __restrict__ Whh, const float* __restrict__ bih,
    const float* __restrict__ bhh, const float* __restrict__ Wp,
    const float* __restrict__ bp,  float* __restrict__ concat_ws)
{
    __shared__ __align__(16) _Float16 frag[2][2048];  // 2 x 4KB: [kb*512 + lane*8]
    __shared__ float xT[NT][9];                       // x transposed, 8 rows padded
    __shared__ float pc[8][8];

    const int tid = threadIdx.x;
    const int w   = tid >> 6;        // wave 0..7
    const int l   = tid & 63;
    const int r   = l & 15;          // A-fragment gate-col index (0..15)
    const int m4  = l >> 4;          // 0..3
    const int rbh = l & 7;           // this lane's batch row
    const int s   = (l >> 3) & 1;    // q-pair selector
    const int bid = blockIdx.x;
    const int v   = bid >> 3;        // variable
    const int r0  = (bid & 7) << 3;  // batch chunk base (8 rows)
    const int j0  = (w << 4) + (m4 << 2);            // acc col base (4 cols)
    const int jh  = j0 + (s << 1);                   // handler col base (2 cols)

    constexpr float L2E = 1.44269504088896340736f;
    const float SCL0 = -L2E, SCL2 = 2.0f * L2E;

    // ---- stage x[v, r0+rr, :] into xT[t][rr] ----
    {
        const int rr = tid >> 6;          // 0..7
        const int t0 = (tid & 63) << 2;   // 0..252
        const float4 xv = *(const float4*)(x + (size_t)(v * NB + r0 + rr) * NT + t0);
        xT[t0][rr] = xv.x; xT[t0+1][rr] = xv.y; xT[t0+2][rr] = xv.z; xT[t0+3][rr] = xv.w;
    }
    // zero BOTH frag buffers (h0 = 0; rows 8..15 start as duplicate of 0..7)
    ((int4*)frag)[tid] = int4{0, 0, 0, 0};

    // ---- preload PRESCALED Whh A-fragments: A[n=l&15][k=kb*32+(l>>4)*8+e] ----
    half8 afr[3][4];
    #pragma unroll
    for (int g = 0; g < 3; ++g) {
        const float sc = (g == 2) ? SCL2 : SCL0;
        #pragma unroll
        for (int kb = 0; kb < 4; ++kb) {
            const float* wpp = Whh + (size_t)(v * 384 + g * 128 + (w << 4) + r) * 128
                             + kb * 32 + m4 * 8;
            float4 lo = *(const float4*)wpp;
            float4 hi = *(const float4*)(wpp + 4);
            half8 hf;
            hf[0]=(_Float16)(sc*lo.x); hf[1]=(_Float16)(sc*lo.y);
            hf[2]=(_Float16)(sc*lo.z); hf[3]=(_Float16)(sc*lo.w);
            hf[4]=(_Float16)(sc*hi.x); hf[5]=(_Float16)(sc*hi.y);
            hf[6]=(_Float16)(sc*hi.z); hf[7]=(_Float16)(sc*hi.w);
            afr[g][kb] = hf;
        }
    }

    // MFMA C-init (cols j0..j0+3 per reg q):
    //   gates r/z: prescaled (bhh + bih)  [bih folded]
    //   gate  n  : prescaled bhh only     [bih must stay outside r-multiply]
    f32x4 c0i, c1i, c2i;
    #pragma unroll
    for (int q = 0; q < 4; ++q) {
        const int i0 = v * 384 + j0 + q;
        c0i[q] = SCL0 * (bhh[i0] + bih[i0]);
        c1i[q] = SCL0 * (bhh[i0 + 128] + bih[i0 + 128]);
        c2i[q] = SCL2 * bhh[i0 + 256];
    }
    // handler-lane params for cols jh, jh+1
    float wih2[3][2], bihn2[2], wpj2[2];
    #pragma unroll
    for (int q = 0; q < 2; ++q) {
        const int ih = v * 384 + jh + q;
        wih2[0][q] = SCL0 * Wih[ih];
        wih2[1][q] = SCL0 * Wih[ih + 128];
        wih2[2][q] = SCL2 * Wih[ih + 256];
        bihn2[q]   = SCL2 * bih[ih + 256];
        wpj2[q]    = Wp[v * NH + jh + q];
    }

    float h_old[2] = {0.f, 0.f};

    // frag b32-write offset for (cols jh..jh+1, row rbh); mirror at row rbh+8
    // is +8 lane-slots = +64 halfs.
    const int fwoff = (jh >> 5) * 512 + (rbh + 16 * ((jh & 31) >> 3)) * 8 + (jh & 7);
    const int rdoff = l * 8;

    __syncthreads();

    auto step = [&](const _Float16* __restrict__ fb, _Float16* __restrict__ fwb,
                    const float xr) {
        half8 bfr[4];
        #pragma unroll
        for (int kb = 0; kb < 4; ++kb)
            bfr[kb] = *(const half8*)(fb + kb * 512 + rdoff);

        f32x4 acc0 = __builtin_amdgcn_mfma_f32_16x16x32_f16(afr[0][0], bfr[0], c0i, 0, 0, 0);
        f32x4 acc1 = __builtin_amdgcn_mfma_f32_16x16x32_f16(afr[1][0], bfr[0], c1i, 0, 0, 0);
        f32x4 acc2 = __builtin_amdgcn_mfma_f32_16x16x32_f16(afr[2][0], bfr[0], c2i, 0, 0, 0);
        #pragma unroll
        for (int kb = 1; kb < 4; ++kb) {
            acc0 = __builtin_amdgcn_mfma_f32_16x16x32_f16(afr[0][kb], bfr[kb], acc0, 0, 0, 0);
            acc1 = __builtin_amdgcn_mfma_f32_16x16x32_f16(afr[1][kb], bfr[kb], acc1, 0, 0, 0);
            acc2 = __builtin_amdgcn_mfma_f32_16x16x32_f16(afr[2][kb], bfr[kb], acc2, 0, 0, 0);
        }

        // local pick (no cross-lane): s=0 -> regs 0,1 (cols j0..j0+1);
        //                             s=1 -> regs 2,3 (cols j0+2..j0+3)
        const float g0[2] = { s ? acc0[2] : acc0[0], s ? acc0[3] : acc0[1] };
        const float g1[2] = { s ? acc1[2] : acc1[0], s ? acc1[3] : acc1[1] };
        const float g2[2] = { s ? acc2[2] : acc2[0], s ? acc2[3] : acc2[1] };

        half2v hv;
        #pragma unroll
        for (int q = 0; q < 2; ++q) {
            const float srs = fmaf(xr, wih2[0][q], g0[q]);
            const float szs = fmaf(xr, wih2[1][q], g1[q]);
            const float gns = fmaf(xr, wih2[2][q], bihn2[q]);
            const float rg  = __builtin_amdgcn_rcpf(1.f + __builtin_amdgcn_exp2f(srs));
            const float a   = __builtin_amdgcn_exp2f(szs);
            const float ccs = fmaf(rg, g2[q], gns);
            const float b   = __builtin_amdgcn_exp2f(-ccs);
            const float h   = h_old[q];
            const float num = fmaf(b, h - a, a + h);   // a(1-b) + h(1+b)
            const float den = (1.f + a) * (1.f + b);
            const float hn  = num * __builtin_amdgcn_rcpf(den);
            h_old[q] = hn;
            hv[q] = (_Float16)hn;
        }
        *(half2v*)(fwb + fwoff)      = hv;   // row rbh
        *(half2v*)(fwb + fwoff + 64) = hv;   // row rbh+8 (duplicate)
        __syncthreads();
    };

    for (int t = 0; t < NT; t += 2) {
        const float xa = xT[t][rbh];
        const float xb = xT[t + 1][rbh];
        step(&frag[0][0], &frag[1][0], xa);
        step(&frag[1][0], &frag[0][0], xb);
    }

    // ---- epilogue: concat[r0+rbh][v] = sum_j h[rbh][j]*Wp[v][j] + bp[v] ----
    float partial = h_old[0] * wpj2[0] + h_old[1] * wpj2[1];
    partial += __shfl_xor(partial, 8, 64);
    partial += __shfl_xor(partial, 16, 64);
    partial += __shfl_xor(partial, 32, 64);
    if (l < 8) pc[w][l] = partial;
    __syncthreads();
    if (tid < 8) {
        float acc = bp[v];
        #pragma unroll
        for (int ww = 0; ww < 8; ++ww) acc += pc[ww][tid];
        concat_ws[(r0 + tid) * NV + v] = acc;
    }
}

// FC head: concat[64][16] -> relu(W1) -> W2 -> out[64][10]. One small block.
__global__ __launch_bounds__(256, 1) void fc_kernel(
    const float* __restrict__ cws, const float* __restrict__ W1,
    const float* __restrict__ b1,  const float* __restrict__ W2,
    const float* __restrict__ b2,  float* __restrict__ out)
{
    __shared__ float cc[NB][NV + 1];
    __shared__ float hfc[NB][NFC + 1];
    const int tid = threadIdx.x;
    for (int i = tid; i < NB * NV; i += 256) cc[i >> 4][i & 15] = cws[i];
    __syncthreads();

    float w1r[NV];
    #pragma unroll
    for (int q = 0; q < NV; q += 4) {
        float4 t4 = *(const float4*)(W1 + tid * NV + q);
        w1r[q] = t4.x; w1r[q+1] = t4.y; w1r[q+2] = t4.z; w1r[q+3] = t4.w;
    }
    const float bb = b1[tid];
    for (int b = 0; b < NB; ++b) {
        float sacc = bb;
        #pragma unroll
        for (int q = 0; q < NV; ++q) sacc = fmaf(cc[b][q], w1r[q], sacc);
        hfc[b][tid] = fmaxf(sacc, 0.f);
    }
    __syncthreads();

    for (int idx = tid; idx < NB * NC; idx += 256) {
        const int b = idx / NC, c = idx % NC;
        const float* w2r = W2 + c * NFC;
        float sacc = b2[c];
        #pragma unroll 4
        for (int f = 0; f < NFC; f += 4) {
            float4 wv = *(const float4*)(w2r + f);
            sacc = fmaf(hfc[b][f+0], wv.x, sacc);
            sacc = fmaf(hfc[b][f+1], wv.y, sacc);
            sacc = fmaf(hfc[b][f+2], wv.z, sacc);
            sacc = fmaf(hfc[b][f+3], wv.w, sacc);
        }
        out[idx] = sacc;
    }
}

extern "C" void kernel_launch(void* const* d_in, const int* in_sizes, int n_in,
                              void* d_out, int out_size, void* d_ws, size_t ws_size,
                              hipStream_t stream) {
    const float* x   = (const float*)d_in[0];
    const float* Wih = (const float*)d_in[1];
    const float* Whh = (const float*)d_in[2];
    const float* bih = (const float*)d_in[3];
    const float* bhh = (const float*)d_in[4];
    const float* Wp  = (const float*)d_in[5];
    const float* bp  = (const float*)d_in[6];
    const float* W1  = (const float*)d_in[7];
    const float* b1  = (const float*)d_in[8];
    const float* W2  = (const float*)d_in[9];
    const float* b2  = (const float*)d_in[10];
    float* out = (float*)d_out;
    float* cws = (float*)d_ws;  // concat scratch: 64*16 f32 = 4 KB

    gru_scan_kernel<<<dim3(128), dim3(512), 0, stream>>>(x, Wih, Whh, bih, bhh, Wp, bp, cws);
    fc_kernel<<<dim3(1), dim3(256), 0, stream>>>(cws, W1, b1, W2, b2, out);
}

// Round 6
// 199.527 us; speedup vs baseline: 1.3182x; 1.0170x over previous
//
#include <hip/hip_runtime.h>

#define NV  16
#define NB  64
#define NT  256
#define NH  128
#define NFC 256
#define NC  10

typedef _Float16 half8  __attribute__((ext_vector_type(8)));
typedef float    f32x4  __attribute__((ext_vector_type(4)));

// One workgroup = one variable v, FOUR batch rows. 8 waves, 256 WGs (all CUs).
// Per step: gh^T = Whh(384n x 128k) * h^T(128k x 16b) via mfma 16x16x32 f16.
// B slots n, n+4, n+8, n+12 all hold h[row n&3] (handlers write h 4x), so D
// column n duplicates n&3: EVERY lane (n = l&15 = rb + 4s) holds the full gh
// for batch row rb = l&3, cols j0..j0+3, in its OWN accumulator. NO cross-lane
// ops: handler picks acc reg s = (l>>2)&3 (col j = j0+s) via cndmask tree.
// Expansion 4 relative to r2: activation work per CU halves vs round 5, and
// all 256 CUs are active. (Round 3 tried this spread but paid 9 ds_bpermute
// per step in the serial chain; this version has zero LDS-pipe redistribution.)
// C layout (verified r2): col(B slot) = lane&15, row(h-col) = (lane>>4)*4+reg.
// Activation algebra (prescaled weights, division-minimized, verified r2-r5):
//   r = rcp(1+exp2(srs)); a = exp2(szs); b = exp2(-ccs)
//   h' = [a(1-b) + h(1+b)] / [(1+a)(1+b)] ; num = fma(b, h-a, a+h)
// bih of r/z gates folded into MFMA C-init; n-gate bih outside the r-multiply.
__global__ __launch_bounds__(512, 2) void gru_scan_kernel(
    const float* __restrict__ x,   const float* __restrict__ Wih,
    const float* __restrict__ Whh, const float* __restrict__ bih,
    const float* __restrict__ bhh, const float* __restrict__ Wp,
    const float* __restrict__ bp,  float* __restrict__ concat_ws)
{
    __shared__ __align__(16) _Float16 frag[2][2048];  // 2 x 4KB: [kb*512 + slot*8]
    __shared__ float xT[NT][5];                       // x transposed, 4 rows padded
    __shared__ float pc[8][4];

    const int tid = threadIdx.x;
    const int w   = tid >> 6;        // wave 0..7
    const int l   = tid & 63;
    const int r   = l & 15;          // A-fragment gate-col index (0..15)
    const int m4  = l >> 4;          // 0..3
    const int rb  = l & 3;           // this lane's batch row
    const int s   = (l >> 2) & 3;    // this lane's q/col selector
    const int bid = blockIdx.x;
    const int v   = bid >> 4;        // variable
    const int b0  = (bid & 15) << 2; // batch chunk base (4 rows)
    const int j0  = (w << 4) + (m4 << 2);  // acc col base (4 cols)
    const int j   = j0 + s;                // handler col (single)

    constexpr float L2E = 1.44269504088896340736f;
    const float SCL0 = -L2E, SCL2 = 2.0f * L2E;

    // ---- stage x[v, b0+rr, :] into xT[t][rr] ----
    {
        const int rr = tid >> 7;          // 0..3
        const int t0 = (tid & 127) << 1;  // 0..254
        const float2 xv = *(const float2*)(x + (size_t)(v * NB + b0 + rr) * NT + t0);
        xT[t0][rr] = xv.x; xT[t0 + 1][rr] = xv.y;
    }
    // zero BOTH frag buffers (h0 = 0; duplicates of 0 are 0)
    ((int4*)frag)[tid] = int4{0, 0, 0, 0};

    // ---- preload PRESCALED Whh A-fragments: A[n=l&15][k=kb*32+(l>>4)*8+e] ----
    half8 afr[3][4];
    #pragma unroll
    for (int g = 0; g < 3; ++g) {
        const float sc = (g == 2) ? SCL2 : SCL0;
        #pragma unroll
        for (int kb = 0; kb < 4; ++kb) {
            const float* wpp = Whh + (size_t)(v * 384 + g * 128 + (w << 4) + r) * 128
                             + kb * 32 + m4 * 8;
            float4 lo = *(const float4*)wpp;
            float4 hi = *(const float4*)(wpp + 4);
            half8 hf;
            hf[0]=(_Float16)(sc*lo.x); hf[1]=(_Float16)(sc*lo.y);
            hf[2]=(_Float16)(sc*lo.z); hf[3]=(_Float16)(sc*lo.w);
            hf[4]=(_Float16)(sc*hi.x); hf[5]=(_Float16)(sc*hi.y);
            hf[6]=(_Float16)(sc*hi.z); hf[7]=(_Float16)(sc*hi.w);
            afr[g][kb] = hf;
        }
    }

    // MFMA C-init (cols j0..j0+3 per reg q):
    //   gates r/z: prescaled (bhh + bih)  [bih folded]
    //   gate  n  : prescaled bhh only     [bih must stay outside r-multiply]
    f32x4 c0i, c1i, c2i;
    #pragma unroll
    for (int q = 0; q < 4; ++q) {
        const int i0 = v * 384 + j0 + q;
        c0i[q] = SCL0 * (bhh[i0] + bih[i0]);
        c1i[q] = SCL0 * (bhh[i0 + 128] + bih[i0 + 128]);
        c2i[q] = SCL2 * bhh[i0 + 256];
    }
    // handler-lane params for single col j
    const int ih = v * 384 + j;
    const float wih0 = SCL0 * Wih[ih];
    const float wih1 = SCL0 * Wih[ih + 128];
    const float wihn = SCL2 * Wih[ih + 256];
    const float bihn = SCL2 * bih[ih + 256];
    const float wpj  = Wp[v * NH + j];

    float h_old = 0.f;

    // frag b16-write offset for (col j, slot rb); duplicates at slots rb+4k
    // are +k*32 halfs.
    const int fwoff = (j >> 5) * 512 + (rb + 16 * ((j & 31) >> 3)) * 8 + (j & 7);
    const int rdoff = l * 8;

    __syncthreads();

    auto step = [&](const _Float16* __restrict__ fb, _Float16* __restrict__ fwb,
                    const float xr) {
        half8 bfr[4];
        #pragma unroll
        for (int kb = 0; kb < 4; ++kb)
            bfr[kb] = *(const half8*)(fb + kb * 512 + rdoff);

        f32x4 acc0 = __builtin_amdgcn_mfma_f32_16x16x32_f16(afr[0][0], bfr[0], c0i, 0, 0, 0);
        f32x4 acc1 = __builtin_amdgcn_mfma_f32_16x16x32_f16(afr[1][0], bfr[0], c1i, 0, 0, 0);
        f32x4 acc2 = __builtin_amdgcn_mfma_f32_16x16x32_f16(afr[2][0], bfr[0], c2i, 0, 0, 0);
        #pragma unroll
        for (int kb = 1; kb < 4; ++kb) {
            acc0 = __builtin_amdgcn_mfma_f32_16x16x32_f16(afr[0][kb], bfr[kb], acc0, 0, 0, 0);
            acc1 = __builtin_amdgcn_mfma_f32_16x16x32_f16(afr[1][kb], bfr[kb], acc1, 0, 0, 0);
            acc2 = __builtin_amdgcn_mfma_f32_16x16x32_f16(afr[2][kb], bfr[kb], acc2, 0, 0, 0);
        }

        // local pick (no cross-lane): gv = acc[s] via 2-level cndmask
        const bool s1 = (s & 1) != 0, s2 = (s & 2) != 0;
        const float g0 = s2 ? (s1 ? acc0[3] : acc0[2]) : (s1 ? acc0[1] : acc0[0]);
        const float g1 = s2 ? (s1 ? acc1[3] : acc1[2]) : (s1 ? acc1[1] : acc1[0]);
        const float g2 = s2 ? (s1 ? acc2[3] : acc2[2]) : (s1 ? acc2[1] : acc2[0]);

        const float srs = fmaf(xr, wih0, g0);
        const float szs = fmaf(xr, wih1, g1);
        const float gns = fmaf(xr, wihn, bihn);
        const float rg  = __builtin_amdgcn_rcpf(1.f + __builtin_amdgcn_exp2f(srs));
        const float a   = __builtin_amdgcn_exp2f(szs);
        const float ccs = fmaf(rg, g2, gns);
        const float b   = __builtin_amdgcn_exp2f(-ccs);
        const float h   = h_old;
        const float num = fmaf(b, h - a, a + h);   // a(1-b) + h(1+b)
        const float den = (1.f + a) * (1.f + b);
        const float hn  = num * __builtin_amdgcn_rcpf(den);
        h_old = hn;
        const _Float16 hv = (_Float16)hn;
        fwb[fwoff]      = hv;   // slot rb
        fwb[fwoff + 32] = hv;   // slot rb+4
        fwb[fwoff + 64] = hv;   // slot rb+8
        fwb[fwoff + 96] = hv;   // slot rb+12
        __syncthreads();
    };

    for (int t = 0; t < NT; t += 2) {
        const float xa = xT[t][rb];
        const float xb = xT[t + 1][rb];
        step(&frag[0][0], &frag[1][0], xa);
        step(&frag[1][0], &frag[0][0], xb);
    }

    // ---- epilogue: concat[b0+rb][v] = sum_j h[rb][j]*Wp[v][j] + bp[v] ----
    float partial = h_old * wpj;
    partial += __shfl_xor(partial, 4, 64);    // over s (low bit)
    partial += __shfl_xor(partial, 8, 64);    // over s (high bit)
    partial += __shfl_xor(partial, 16, 64);   // over m4
    partial += __shfl_xor(partial, 32, 64);
    if (l < 4) pc[w][l] = partial;
    __syncthreads();
    if (tid < 4) {
        float acc = bp[v];
        #pragma unroll
        for (int ww = 0; ww < 8; ++ww) acc += pc[ww][tid];
        concat_ws[(b0 + tid) * NV + v] = acc;
    }
}

// FC head: concat[64][16] -> relu(W1) -> W2 -> out[64][10]. One small block.
__global__ __launch_bounds__(256, 1) void fc_kernel(
    const float* __restrict__ cws, const float* __restrict__ W1,
    const float* __restrict__ b1,  const float* __restrict__ W2,
    const float* __restrict__ b2,  float* __restrict__ out)
{
    __shared__ float cc[NB][NV + 1];
    __shared__ float hfc[NB][NFC + 1];
    const int tid = threadIdx.x;
    for (int i = tid; i < NB * NV; i += 256) cc[i >> 4][i & 15] = cws[i];
    __syncthreads();

    float w1r[NV];
    #pragma unroll
    for (int q = 0; q < NV; q += 4) {
        float4 t4 = *(const float4*)(W1 + tid * NV + q);
        w1r[q] = t4.x; w1r[q+1] = t4.y; w1r[q+2] = t4.z; w1r[q+3] = t4.w;
    }
    const float bb = b1[tid];
    for (int b = 0; b < NB; ++b) {
        float sacc = bb;
        #pragma unroll
        for (int q = 0; q < NV; ++q) sacc = fmaf(cc[b][q], w1r[q], sacc);
        hfc[b][tid] = fmaxf(sacc, 0.f);
    }
    __syncthreads();

    for (int idx = tid; idx < NB * NC; idx += 256) {
        const int b = idx / NC, c = idx % NC;
        const float* w2r = W2 + c * NFC;
        float sacc = b2[c];
        #pragma unroll 4
        for (int f = 0; f < NFC; f += 4) {
            float4 wv = *(const float4*)(w2r + f);
            sacc = fmaf(hfc[b][f+0], wv.x, sacc);
            sacc = fmaf(hfc[b][f+1], wv.y, sacc);
            sacc = fmaf(hfc[b][f+2], wv.z, sacc);
            sacc = fmaf(hfc[b][f+3], wv.w, sacc);
        }
        out[idx] = sacc;
    }
}

extern "C" void kernel_launch(void* const* d_in, const int* in_sizes, int n_in,
                              void* d_out, int out_size, void* d_ws, size_t ws_size,
                              hipStream_t stream) {
    const float* x   = (const float*)d_in[0];
    const float* Wih = (const float*)d_in[1];
    const float* Whh = (const float*)d_in[2];
    const float* bih = (const float*)d_in[3];
    const float* bhh = (const float*)d_in[4];
    const float* Wp  = (const float*)d_in[5];
    const float* bp  = (const float*)d_in[6];
    const float* W1  = (const float*)d_in[7];
    const float* b1  = (const float*)d_in[8];
    const float* W2  = (const float*)d_in[9];
    const float* b2  = (const float*)d_in[10];
    float* out = (float*)d_out;
    float* cws = (float*)d_ws;  // concat scratch: 64*16 f32 = 4 KB

    gru_scan_kernel<<<dim3(256), dim3(512), 0, stream>>>(x, Wih, Whh, bih, bhh, Wp, bp, cws);
    fc_kernel<<<dim3(1), dim3(256), 0, stream>>>(cws, W1, b1, W2, b2, out);
}